// Round 2
// baseline (469.607 us; speedup 1.0000x reference)
//
#include <hip/hip_runtime.h>
#include <math.h>

using short8  = __attribute__((ext_vector_type(8))) short;
using ushort8 = __attribute__((ext_vector_type(8))) unsigned short;
using f32x4   = __attribute__((ext_vector_type(4))) float;

#define NBLKS 512
#define BPAD  800   // padded bucket count (nbuck <= 800)
#define EB 8
#define BSTR 328    // B_lds stride in shorts: 656B -> col stride = 4 banks, conflict-free

__device__ __forceinline__ unsigned short f2bf(float f) {
    unsigned u = __float_as_uint(f);
    unsigned r = u + 0x7FFF + ((u >> 16) & 1);   // round-to-nearest-even
    return (unsigned short)(r >> 16);
}
__device__ __forceinline__ float bf2f(unsigned short v) {
    return __uint_as_float((unsigned)v << 16);
}
// packed f32x2 -> bf16x2, RTNE in HW (bit-identical to f2bf for finite inputs)
__device__ __forceinline__ unsigned cvt2(float lo, float hi) {
    unsigned r;
    asm("v_cvt_pk_bf16_f32 %0, %1, %2" : "=v"(r) : "v"(lo), "v"(hi));
    return r;
}
// async global->LDS, 16B per lane; lds base must be wave-uniform (HW adds lane*16)
__device__ __forceinline__ void glds16(const void* g, void* l) {
    __builtin_amdgcn_global_load_lds(
        (const __attribute__((address_space(1))) unsigned*)g,
        (__attribute__((address_space(3))) unsigned*)l, 16, 0, 0);
}

// ---------------- edge dtype detect ----------------

__global__ void detect64_kernel(const int* __restrict__ ei, int E, int* __restrict__ flag) {
    __shared__ int any;
    if (threadIdx.x == 0) any = 0;
    __syncthreads();
    for (int i = threadIdx.x; i < 1024; i += 256) {
        if (ei[2 * i + 1] != 0) { any = 1; break; }
    }
    __syncthreads();
    if (threadIdx.x == 0) *flag = (any ? 0 : 1);  // 1 => int64
}

// ---------------- CSR build: two-level counting sort, zero global atomics ----------------

__global__ __launch_bounds__(256) void binA_kernel(
    const int* __restrict__ ei, int E, int N, const int* __restrict__ flag,
    int nbuck, int* __restrict__ hist, int chunk) {
    __shared__ int lh[BPAD];
    for (int i = threadIdx.x; i < nbuck; i += 256) lh[i] = 0;
    __syncthreads();
    int is64 = *flag;
    int Etot = E + N;
    int beg = blockIdx.x * chunk, end = min(Etot, beg + chunk);
    for (int i = beg + threadIdx.x; i < end; i += 256) {
        int d = (i < E) ? (is64 ? ei[2 * (E + i)] : ei[E + i]) : (i - E);
        atomicAdd(&lh[d >> 7], 1);
    }
    __syncthreads();
    for (int i = threadIdx.x; i < nbuck; i += 256) hist[blockIdx.x * BPAD + i] = lh[i];
}

__global__ void scanBlocks_kernel(int* __restrict__ hist, int nbuck, int* __restrict__ bucketTotal) {
    int bin = blockIdx.x * 256 + threadIdx.x;
    if (bin >= nbuck) return;
    int run = 0;
    for (int b = 0; b < NBLKS; b++) {
        int v = hist[b * BPAD + bin];
        hist[b * BPAD + bin] = run;
        run += v;
    }
    bucketTotal[bin] = run;
}

__global__ void scanBucket_kernel(const int* __restrict__ bucketTotal, int nbuck,
                                  int* __restrict__ bucketBase) {
    __shared__ int s[1024];
    int t = threadIdx.x;
    int v = (t < nbuck) ? bucketTotal[t] : 0;
    s[t] = v;
    __syncthreads();
    for (int off = 1; off < 1024; off <<= 1) {
        int x = (t >= off) ? s[t - off] : 0;
        __syncthreads();
        s[t] += x;
        __syncthreads();
    }
    if (t < nbuck) bucketBase[t] = s[t] - v;
    if (t == nbuck - 1) bucketBase[nbuck] = s[t];
}

__global__ __launch_bounds__(256) void binB_kernel(
    const int* __restrict__ ei, int E, int N, const int* __restrict__ flag,
    int nbuck, const int* __restrict__ hist, const int* __restrict__ bucketBase,
    int* __restrict__ tmp, int chunk) {
    __shared__ int cur[BPAD];
    for (int i = threadIdx.x; i < nbuck; i += 256)
        cur[i] = bucketBase[i] + hist[blockIdx.x * BPAD + i];
    __syncthreads();
    int is64 = *flag;
    int Etot = E + N;
    int beg = blockIdx.x * chunk, end = min(Etot, beg + chunk);
    for (int i = beg + threadIdx.x; i < end; i += 256) {
        int s, d;
        if (i < E) {
            if (is64) { s = ei[2 * i]; d = ei[2 * (E + i)]; }
            else      { s = ei[i];     d = ei[E + i]; }
        } else { s = i - E; d = i - E; }
        int pos = atomicAdd(&cur[d >> 7], 1);
        tmp[pos] = ((d & 127) << 17) | s;   // src < 2^17
    }
}

__global__ __launch_bounds__(256) void binC_kernel(
    const int* __restrict__ tmp, const int* __restrict__ bucketBase, int nbuck,
    int N, int Etot, int* __restrict__ rowptr, int* __restrict__ col) {
    __shared__ int lh[128];
    __shared__ int cur[128];
    int g = blockIdx.x;
    int t = threadIdx.x;
    int beg = bucketBase[g], end = bucketBase[g + 1];
    if (t < 128) lh[t] = 0;
    __syncthreads();
    for (int i = beg + t; i < end; i += 256) atomicAdd(&lh[tmp[i] >> 17], 1);
    __syncthreads();
    int c = (t < 128) ? lh[t] : 0;
    for (int off = 1; off < 128; off <<= 1) {
        int x = 0;
        if (t < 128 && t >= off) x = lh[t - off];
        __syncthreads();
        if (t < 128) lh[t] += x;
        __syncthreads();
    }
    if (t < 128) {
        int excl = lh[t] - c;
        cur[t] = beg + excl;
        int node = g * 128 + t;
        if (node < N) rowptr[node] = beg + excl;
    }
    if (g == 0 && t == 0) rowptr[N] = Etot;
    if (g == 0 && t < 16) col[Etot + t] = 0;   // pad so agg can read past end safely
    __syncthreads();
    for (int i = beg + t; i < end; i += 256) {
        int v = tmp[i];
        int pos = atomicAdd(&cur[v >> 17], 1);
        col[pos] = v & 0x1FFFF;
    }
}

// ---------------- GEMM 1 (MFMA bf16): h1(bf16) = x @ W1, fused e_src/e_dst ----------------
// A staged fp32 via global_load_lds dwordx4 (coalesced 128B/row, no VGPR roundtrip),
// double-buffered, source-pre-swizzled (slot ^= row&7) so fragment ds_read_b128 is
// bank-conflict-free on the linear LDS layout. bf16 conversion at fragment read via
// v_cvt_pk_bf16_f32. B (W1) staged once as bf16 [col][k]. One barrier per K-tile.
// K tail (300..319): A holds finite junk, annihilated by zero-padded B rows.

__global__ __launch_bounds__(256) void gemm1_mfma_kernel(
    const float* __restrict__ x, const float* __restrict__ W,
    const float* __restrict__ asrc, const float* __restrict__ adst,
    unsigned short* __restrict__ hbf, float* __restrict__ es, float* __restrict__ ed, int N) {
    __shared__ __align__(16) unsigned short B_lds[64 * BSTR];   // 41984 B
    __shared__ __align__(16) float A_lds[2][128 * 32];          // 32768 B
    const int tx = threadIdx.x;
    const int wv = tx >> 6;          // 0..3
    const int lane = tx & 63;
    const int l15 = lane & 15;
    const int quad = lane >> 4;
    const int rowBase = blockIdx.x * 128;

    const int sRowL = lane >> 3;     // 0..7: row within one glds instruction
    const int sSlot = lane & 7;      // 16B slot within row

    // stage one K-tile of A: wave wv covers rows wv*32..wv*32+31, 4 instrs x 8 rows
    auto stageA = [&](int buf, int k0) {
#pragma unroll
        for (int j = 0; j < 4; j++) {
            int row   = wv * 32 + j * 8 + sRowL;
            int grow  = min(rowBase + row, N - 1);
            int gslot = sSlot ^ (row & 7);              // source pre-swizzle
            int koff  = k0 + gslot * 4;
            size_t srcOff = (koff + 4 <= 300) ? ((size_t)grow * 300 + koff) : 0;
            glds16(x + srcOff, &A_lds[buf][(wv * 32 + j * 8) * 32]);
        }
    };

    f32x4 acc[2][4];
#pragma unroll
    for (int rt = 0; rt < 2; rt++)
#pragma unroll
        for (int ct = 0; ct < 4; ct++) acc[rt][ct] = (f32x4){0.f, 0.f, 0.f, 0.f};

    // issue A tile 0, then stage B (overlaps with the async A loads)
    stageA(0, 0);
    {
        int colB = tx & 63;
        int g4 = tx >> 6;
#pragma unroll
        for (int j = 0; j < 40; j++) {
            int k = (g4 * 40 + j) * 2;
            float v0 = (k < 300)     ? W[(size_t)k * 64 + colB]       : 0.f;
            float v1 = (k + 1 < 300) ? W[(size_t)(k + 1) * 64 + colB] : 0.f;
            *(unsigned*)&B_lds[colB * BSTR + k] = cvt2(v0, v1);
        }
    }
    __syncthreads();   // drains vmcnt (A tile0) + lgkm (B writes)

    for (int t = 0; t < 10; t++) {
        int cur = t & 1;
        if (t < 9) stageA(cur ^ 1, (t + 1) * 32);
        short8 af[2];
#pragma unroll
        for (int rt = 0; rt < 2; rt++) {
            int row = wv * 32 + rt * 16 + l15;
            const float* ab = &A_lds[cur][row * 32];
            int m = row & 7;
            f32x4 fa = *(const f32x4*)(ab + (((2 * quad)     ^ m) * 4));
            f32x4 fb = *(const f32x4*)(ab + (((2 * quad + 1) ^ m) * 4));
            union { unsigned u[4]; short8 s; } cv;
            cv.u[0] = cvt2(fa[0], fa[1]);
            cv.u[1] = cvt2(fa[2], fa[3]);
            cv.u[2] = cvt2(fb[0], fb[1]);
            cv.u[3] = cvt2(fb[2], fb[3]);
            af[rt] = cv.s;
        }
        const int k0 = t * 32;
#pragma unroll
        for (int ct = 0; ct < 4; ct++) {
            short8 bfr = *(const short8*)&B_lds[(ct * 16 + l15) * BSTR + k0 + quad * 8];
            acc[0][ct] = __builtin_amdgcn_mfma_f32_16x16x32_bf16(af[0], bfr, acc[0][ct], 0, 0, 0);
            acc[1][ct] = __builtin_amdgcn_mfma_f32_16x16x32_bf16(af[1], bfr, acc[1][ct], 0, 0, 0);
        }
        __syncthreads();   // stage(t+1) landed; buf[cur] reads complete
    }

    float as_v[4], ad_v[4];
#pragma unroll
    for (int ct = 0; ct < 4; ct++) {
        as_v[ct] = asrc[ct * 16 + l15];
        ad_v[ct] = adst[ct * 16 + l15];
    }
#pragma unroll
    for (int rt = 0; rt < 2; rt++) {
#pragma unroll
        for (int reg = 0; reg < 4; reg++) {
            int row = rowBase + wv * 32 + rt * 16 + quad * 4 + reg;
            bool ok = (row < N);
#pragma unroll
            for (int ct = 0; ct < 4; ct++) {
                float v = acc[rt][ct][reg];
                if (ok) hbf[(size_t)row * 64 + ct * 16 + l15] = f2bf(v);
                float ps = v * as_v[ct];
                float pd = v * ad_v[ct];
                ps += __shfl_xor(ps, 1); ps += __shfl_xor(ps, 2); ps += __shfl_xor(ps, 4);
                pd += __shfl_xor(pd, 1); pd += __shfl_xor(pd, 2); pd += __shfl_xor(pd, 4);
                if ((lane & 7) == 0 && ok) {
                    int head = 2 * ct + ((lane >> 3) & 1);
                    es[row * 8 + head] = ps;
                    ed[row * 8 + head] = pd;
                }
            }
        }
    }
}

// ---------------- GEMM 2 (MFMA bf16): h2(bf16) = h1p(bf16) @ W2, fused scalar e_src/e_dst ----------------

__global__ __launch_bounds__(256) void gemm2_mfma_kernel(
    const unsigned short* __restrict__ xin, const float* __restrict__ W,
    const float* __restrict__ asrc, const float* __restrict__ adst,
    unsigned short* __restrict__ hbf, float* __restrict__ es, float* __restrict__ ed, int N) {
    __shared__ __align__(16) unsigned short A_lds[128 * 72];
    __shared__ __align__(16) unsigned short B_lds[64 * 72];
    const int tx = threadIdx.x;
    const int wv = tx >> 6;
    const int lane = tx & 63;
    const int l15 = lane & 15;
    const int quad = lane >> 4;
    const int rowBase = blockIdx.x * 128;

    f32x4 acc[2][4];
#pragma unroll
    for (int rt = 0; rt < 2; rt++)
#pragma unroll
        for (int ct = 0; ct < 4; ct++) acc[rt][ct] = (f32x4){0.f, 0.f, 0.f, 0.f};

    // stage B: full 64x64 (transposed into [col][k], stride 72)
    {
        int colB = tx & 63;
        int kk = (tx >> 6) * 16;
#pragma unroll
        for (int j = 0; j < 16; j++)
            B_lds[colB * 72 + kk + j] = f2bf(W[(size_t)(kk + j) * 64 + colB]);
    }
    // stage A: 128 rows x 64 k, bf16 input -> straight copy (ushort8 = 16B loads)
    {
        int kq = tx & 7, r0 = tx >> 3;
        const ushort8 z = (ushort8){0, 0, 0, 0, 0, 0, 0, 0};
#pragma unroll
        for (int p = 0; p < 4; p++) {
            int row = p * 32 + r0;
            int grow = rowBase + row;
            ushort8 v = z;
            if (grow < N) v = *(const ushort8*)&xin[(size_t)grow * 64 + kq * 8];
            *(ushort8*)&A_lds[row * 72 + kq * 8] = v;
        }
    }
    __syncthreads();
#pragma unroll
    for (int c = 0; c < 2; c++) {
        short8 af[2], bfr[4];
#pragma unroll
        for (int rt = 0; rt < 2; rt++)
            af[rt] = *(const short8*)&A_lds[(wv * 32 + rt * 16 + l15) * 72 + quad * 8 + c * 32];
#pragma unroll
        for (int ct = 0; ct < 4; ct++)
            bfr[ct] = *(const short8*)&B_lds[(ct * 16 + l15) * 72 + quad * 8 + c * 32];
#pragma unroll
        for (int rt = 0; rt < 2; rt++)
#pragma unroll
            for (int ct = 0; ct < 4; ct++)
                acc[rt][ct] = __builtin_amdgcn_mfma_f32_16x16x32_bf16(af[rt], bfr[ct], acc[rt][ct], 0, 0, 0);
    }

    float as_v[4], ad_v[4];
#pragma unroll
    for (int ct = 0; ct < 4; ct++) {
        as_v[ct] = asrc[ct * 16 + l15];
        ad_v[ct] = adst[ct * 16 + l15];
    }
#pragma unroll
    for (int rt = 0; rt < 2; rt++) {
#pragma unroll
        for (int reg = 0; reg < 4; reg++) {
            int row = rowBase + wv * 32 + rt * 16 + quad * 4 + reg;
            bool ok = (row < N);
            float ps = 0.f, pd = 0.f;
#pragma unroll
            for (int ct = 0; ct < 4; ct++) {
                float v = acc[rt][ct][reg];
                if (ok) hbf[(size_t)row * 64 + ct * 16 + l15] = f2bf(v);
                ps = fmaf(v, as_v[ct], ps);
                pd = fmaf(v, ad_v[ct], pd);
            }
            ps += __shfl_xor(ps, 1); ps += __shfl_xor(ps, 2);
            ps += __shfl_xor(ps, 4); ps += __shfl_xor(ps, 8);
            pd += __shfl_xor(pd, 1); pd += __shfl_xor(pd, 2);
            pd += __shfl_xor(pd, 4); pd += __shfl_xor(pd, 8);
            if (l15 == 0 && ok) { es[row] = ps; ed[row] = pd; }
        }
    }
}

// ---------------- fused aggregations: softmax weights computed inline ----------------
// lane = 32*half + fl; lane handles features {2fl, 2fl+1} of edge (i + 2j + half).
// Softmax shift dropped (logits bounded, clamp at 30); denominator accumulated inline.
// Out-of-range edge slots clamp their index to `beg` (every node has a self-loop so
// end > beg): the wasted gathers hit already-fetched lines instead of scattering.

__global__ __launch_bounds__(256) void agg1f_kernel(
    const int* __restrict__ rowptr, const int* __restrict__ col,
    const unsigned short* __restrict__ hbf, const float* __restrict__ es,
    const float* __restrict__ ed, const float* __restrict__ b,
    unsigned int* __restrict__ outbf, int N) {
    int node = blockIdx.x * 4 + (threadIdx.x >> 6);
    int lane = threadIdx.x & 63;
    if (node >= N) return;
    int half = lane >> 5, fl = lane & 31;
    int f0 = fl * 2, hh = fl >> 2;
    int beg = rowptr[node], end = rowptr[node + 1];
    float edv = ed[node * 8 + hh];
    float acc0 = 0.f, acc1 = 0.f, lsum = 0.f;
    for (int i = beg; i < end; i += 16) {
        int ei_[EB], ss[EB];
        float ev[EB];
        unsigned hp[EB];
#pragma unroll
        for (int j = 0; j < EB; j++) ei_[j] = i + 2 * j + half;
#pragma unroll
        for (int j = 0; j < EB; j++) ss[j] = col[(ei_[j] < end) ? ei_[j] : beg];
#pragma unroll
        for (int j = 0; j < EB; j++) ev[j] = es[ss[j] * 8 + hh];
#pragma unroll
        for (int j = 0; j < EB; j++) hp[j] = *(const unsigned*)&hbf[(size_t)ss[j] * 64 + f0];
#pragma unroll
        for (int j = 0; j < EB; j++) {
            float e = ev[j] + edv;
            e = (e > 0.f) ? e : 0.2f * e;
            float wj = __expf(fminf(e, 30.f));
            wj = (ei_[j] < end) ? wj : 0.f;
            lsum += wj;
            float lo = __uint_as_float(hp[j] << 16);
            float hi = __uint_as_float(hp[j] & 0xFFFF0000u);
            acc0 = fmaf(wj, lo, acc0);
            acc1 = fmaf(wj, hi, acc1);
        }
    }
    acc0 += __shfl_xor(acc0, 32);
    acc1 += __shfl_xor(acc1, 32);
    lsum += __shfl_xor(lsum, 32);
    float rinv = 1.f / lsum;
    float o0 = acc0 * rinv + b[f0];
    float o1 = acc1 * rinv + b[f0 + 1];
    o0 = (o0 > 0.f) ? o0 : expm1f(o0);
    o1 = (o1 > 0.f) ? o1 : expm1f(o1);
    if (half == 0) {
        unsigned pk = (unsigned)f2bf(o0) | ((unsigned)f2bf(o1) << 16);
        outbf[((size_t)node * 64 + f0) >> 1] = pk;
    }
}

__global__ __launch_bounds__(256) void agg2f_kernel(
    const int* __restrict__ rowptr, const int* __restrict__ col,
    const unsigned short* __restrict__ hbf, const float* __restrict__ es,
    const float* __restrict__ ed, const float* __restrict__ b,
    float* __restrict__ out, int N) {
    int node = blockIdx.x * 4 + (threadIdx.x >> 6);
    int lane = threadIdx.x & 63;
    if (node >= N) return;
    int half = lane >> 5, fl = lane & 31;
    int f0 = fl * 2;
    int beg = rowptr[node], end = rowptr[node + 1];
    float edv = ed[node];
    float acc0 = 0.f, acc1 = 0.f, lsum = 0.f;
    for (int i = beg; i < end; i += 16) {
        int ei_[EB], ss[EB];
        float ev[EB];
        unsigned hp[EB];
#pragma unroll
        for (int j = 0; j < EB; j++) ei_[j] = i + 2 * j + half;
#pragma unroll
        for (int j = 0; j < EB; j++) ss[j] = col[(ei_[j] < end) ? ei_[j] : beg];
#pragma unroll
        for (int j = 0; j < EB; j++) ev[j] = es[ss[j]];
#pragma unroll
        for (int j = 0; j < EB; j++) hp[j] = *(const unsigned*)&hbf[(size_t)ss[j] * 64 + f0];
#pragma unroll
        for (int j = 0; j < EB; j++) {
            float e = ev[j] + edv;
            e = (e > 0.f) ? e : 0.2f * e;
            float wj = __expf(fminf(e, 30.f));
            wj = (ei_[j] < end) ? wj : 0.f;
            lsum += wj;
            float lo = __uint_as_float(hp[j] << 16);
            float hi = __uint_as_float(hp[j] & 0xFFFF0000u);
            acc0 = fmaf(wj, lo, acc0);
            acc1 = fmaf(wj, hi, acc1);
        }
    }
    acc0 += __shfl_xor(acc0, 32);
    acc1 += __shfl_xor(acc1, 32);
    lsum += __shfl_xor(lsum, 32);
    float rinv = 1.f / lsum;
    float o0 = acc0 * rinv + b[f0];
    float o1 = acc1 * rinv + b[f0 + 1];
    // log_softmax over 64 features (each half holds all 32 feature-pairs after combine)
    float M = fmaxf(o0, o1);
    M = fmaxf(M, __shfl_xor(M, 1));  M = fmaxf(M, __shfl_xor(M, 2));
    M = fmaxf(M, __shfl_xor(M, 4));  M = fmaxf(M, __shfl_xor(M, 8));
    M = fmaxf(M, __shfl_xor(M, 16));
    float se = __expf(o0 - M) + __expf(o1 - M);
    se += __shfl_xor(se, 1);  se += __shfl_xor(se, 2);
    se += __shfl_xor(se, 4);  se += __shfl_xor(se, 8);
    se += __shfl_xor(se, 16);
    float ls = logf(se);
    if (half == 0) {
        float2 r = make_float2(o0 - M - ls, o1 - M - ls);
        *(float2*)&out[(size_t)node * 64 + f0] = r;
    }
}

// ---------------- launch ----------------

extern "C" void kernel_launch(void* const* d_in, const int* in_sizes, int n_in,
                              void* d_out, int out_size, void* d_ws, size_t ws_size,
                              hipStream_t stream) {
    const float* x   = (const float*)d_in[0];
    const int*   ei  = (const int*)d_in[1];
    const float* W1  = (const float*)d_in[2];
    const float* as1 = (const float*)d_in[3];
    const float* ad1 = (const float*)d_in[4];
    const float* b1  = (const float*)d_in[5];
    const float* W2  = (const float*)d_in[6];
    const float* as2 = (const float*)d_in[7];
    const float* ad2 = (const float*)d_in[8];
    const float* b2  = (const float*)d_in[9];
    const int N = in_sizes[0] / 300;
    const int E = in_sizes[1] / 2;
    const int Etot = E + N;
    const int nbuck = (N + 127) >> 7;   // <= 800
    (void)n_in; (void)out_size; (void)ws_size;

    char* w = (char*)d_ws;
    auto alloc = [&](size_t bytes) -> char* {
        char* p = w;
        w += (bytes + 255) & ~(size_t)255;
        return p;
    };
    int*   flag        = (int*)alloc(256);
    int*   hist        = (int*)alloc((size_t)NBLKS * BPAD * 4);
    int*   bucketTotal = (int*)alloc((size_t)(BPAD + 1) * 4);
    int*   bucketBase  = (int*)alloc((size_t)(BPAD + 1) * 4);
    int*   tmp         = (int*)alloc((size_t)(Etot + 16) * 4);
    int*   rowptr      = (int*)alloc((size_t)(N + 1) * 4);
    int*   col         = (int*)alloc((size_t)(Etot + 16) * 4);
    unsigned short* h1  = (unsigned short*)alloc((size_t)N * 64 * 2);
    unsigned short* h1p = (unsigned short*)alloc((size_t)N * 64 * 2);
    float* es1         = (float*)alloc((size_t)N * 8 * 4);
    float* ed1         = (float*)alloc((size_t)N * 8 * 4);
    float* es2         = (float*)alloc((size_t)N * 4);
    float* ed2         = (float*)alloc((size_t)N * 4);
    unsigned short* h2 = h1;        // h1 dead after agg1

    detect64_kernel<<<1, 256, 0, stream>>>(ei, E, flag);

    int chunk = (Etot + NBLKS - 1) / NBLKS;
    binA_kernel<<<NBLKS, 256, 0, stream>>>(ei, E, N, flag, nbuck, hist, chunk);
    scanBlocks_kernel<<<(nbuck + 255) / 256, 256, 0, stream>>>(hist, nbuck, bucketTotal);
    scanBucket_kernel<<<1, 1024, 0, stream>>>(bucketTotal, nbuck, bucketBase);
    binB_kernel<<<NBLKS, 256, 0, stream>>>(ei, E, N, flag, nbuck, hist, bucketBase, tmp, chunk);
    binC_kernel<<<nbuck, 256, 0, stream>>>(tmp, bucketBase, nbuck, N, Etot, rowptr, col);

    gemm1_mfma_kernel<<<(N + 127) / 128, 256, 0, stream>>>(x, W1, as1, ad1, h1, es1, ed1, N);
    agg1f_kernel<<<(N + 3) / 4, 256, 0, stream>>>(rowptr, col, h1, es1, ed1, b1,
                                                  (unsigned int*)h1p, N);
    gemm2_mfma_kernel<<<(N + 127) / 128, 256, 0, stream>>>(h1p, W2, as2, ad2, h2, es2, ed2, N);
    agg2f_kernel<<<(N + 3) / 4, 256, 0, stream>>>(rowptr, col, h2, es2, ed2, b2, (float*)d_out, N);
}

// Round 3
// 463.530 us; speedup vs baseline: 1.0131x; 1.0131x over previous
//
#include <hip/hip_runtime.h>
#include <math.h>

using short8  = __attribute__((ext_vector_type(8))) short;
using ushort8 = __attribute__((ext_vector_type(8))) unsigned short;
using f32x4   = __attribute__((ext_vector_type(4))) float;

#define NBLKS 512
#define BPAD  800   // padded bucket count (nbuck <= 800)
#define EB 8

__device__ __forceinline__ unsigned short f2bf(float f) {
    unsigned u = __float_as_uint(f);
    unsigned r = u + 0x7FFF + ((u >> 16) & 1);   // round-to-nearest-even
    return (unsigned short)(r >> 16);
}
__device__ __forceinline__ float bf2f(unsigned short v) {
    return __uint_as_float((unsigned)v << 16);
}
// packed f32x2 -> bf16x2, RTNE in HW (bit-identical to f2bf for finite inputs)
__device__ __forceinline__ unsigned cvt2(float lo, float hi) {
    unsigned r;
    asm("v_cvt_pk_bf16_f32 %0, %1, %2" : "=v"(r) : "v"(lo), "v"(hi));
    return r;
}
// async global->LDS, 16B per lane; lds base must be wave-uniform (HW adds lane*16)
__device__ __forceinline__ void glds16(const void* g, void* l) {
    __builtin_amdgcn_global_load_lds(
        (const __attribute__((address_space(1))) unsigned*)g,
        (__attribute__((address_space(3))) unsigned*)l, 16, 0, 0);
}

// ---------------- edge dtype detect ----------------

__global__ void detect64_kernel(const int* __restrict__ ei, int E, int* __restrict__ flag) {
    __shared__ int any;
    if (threadIdx.x == 0) any = 0;
    __syncthreads();
    for (int i = threadIdx.x; i < 1024; i += 256) {
        if (ei[2 * i + 1] != 0) { any = 1; break; }
    }
    __syncthreads();
    if (threadIdx.x == 0) *flag = (any ? 0 : 1);  // 1 => int64
}

// ---------------- CSR build: two-level counting sort, zero global atomics ----------------

__global__ __launch_bounds__(256) void binA_kernel(
    const int* __restrict__ ei, int E, int N, const int* __restrict__ flag,
    int nbuck, int* __restrict__ hist, int chunk) {
    __shared__ int lh[BPAD];
    for (int i = threadIdx.x; i < nbuck; i += 256) lh[i] = 0;
    __syncthreads();
    int is64 = *flag;
    int Etot = E + N;
    int beg = blockIdx.x * chunk, end = min(Etot, beg + chunk);
    for (int i = beg + threadIdx.x; i < end; i += 256) {
        int d = (i < E) ? (is64 ? ei[2 * (E + i)] : ei[E + i]) : (i - E);
        atomicAdd(&lh[d >> 7], 1);
    }
    __syncthreads();
    for (int i = threadIdx.x; i < nbuck; i += 256) hist[blockIdx.x * BPAD + i] = lh[i];
}

__global__ void scanBlocks_kernel(int* __restrict__ hist, int nbuck, int* __restrict__ bucketTotal) {
    int bin = blockIdx.x * 256 + threadIdx.x;
    if (bin >= nbuck) return;
    int run = 0;
    for (int b = 0; b < NBLKS; b++) {
        int v = hist[b * BPAD + bin];
        hist[b * BPAD + bin] = run;
        run += v;
    }
    bucketTotal[bin] = run;
}

__global__ void scanBucket_kernel(const int* __restrict__ bucketTotal, int nbuck,
                                  int* __restrict__ bucketBase) {
    __shared__ int s[1024];
    int t = threadIdx.x;
    int v = (t < nbuck) ? bucketTotal[t] : 0;
    s[t] = v;
    __syncthreads();
    for (int off = 1; off < 1024; off <<= 1) {
        int x = (t >= off) ? s[t - off] : 0;
        __syncthreads();
        s[t] += x;
        __syncthreads();
    }
    if (t < nbuck) bucketBase[t] = s[t] - v;
    if (t == nbuck - 1) bucketBase[nbuck] = s[t];
}

__global__ __launch_bounds__(256) void binB_kernel(
    const int* __restrict__ ei, int E, int N, const int* __restrict__ flag,
    int nbuck, const int* __restrict__ hist, const int* __restrict__ bucketBase,
    int* __restrict__ tmp, int chunk) {
    __shared__ int cur[BPAD];
    for (int i = threadIdx.x; i < nbuck; i += 256)
        cur[i] = bucketBase[i] + hist[blockIdx.x * BPAD + i];
    __syncthreads();
    int is64 = *flag;
    int Etot = E + N;
    int beg = blockIdx.x * chunk, end = min(Etot, beg + chunk);
    for (int i = beg + threadIdx.x; i < end; i += 256) {
        int s, d;
        if (i < E) {
            if (is64) { s = ei[2 * i]; d = ei[2 * (E + i)]; }
            else      { s = ei[i];     d = ei[E + i]; }
        } else { s = i - E; d = i - E; }
        int pos = atomicAdd(&cur[d >> 7], 1);
        tmp[pos] = ((d & 127) << 17) | s;   // src < 2^17
    }
}

__global__ __launch_bounds__(256) void binC_kernel(
    const int* __restrict__ tmp, const int* __restrict__ bucketBase, int nbuck,
    int N, int Etot, int* __restrict__ rowptr, int* __restrict__ col) {
    __shared__ int lh[128];
    __shared__ int cur[128];
    int g = blockIdx.x;
    int t = threadIdx.x;
    int beg = bucketBase[g], end = bucketBase[g + 1];
    if (t < 128) lh[t] = 0;
    __syncthreads();
    for (int i = beg + t; i < end; i += 256) atomicAdd(&lh[tmp[i] >> 17], 1);
    __syncthreads();
    int c = (t < 128) ? lh[t] : 0;
    for (int off = 1; off < 128; off <<= 1) {
        int x = 0;
        if (t < 128 && t >= off) x = lh[t - off];
        __syncthreads();
        if (t < 128) lh[t] += x;
        __syncthreads();
    }
    if (t < 128) {
        int excl = lh[t] - c;
        cur[t] = beg + excl;
        int node = g * 128 + t;
        if (node < N) rowptr[node] = beg + excl;
    }
    if (g == 0 && t == 0) rowptr[N] = Etot;
    if (g == 0 && t < 16) col[Etot + t] = 0;   // pad so agg can read past end safely
    __syncthreads();
    for (int i = beg + t; i < end; i += 256) {
        int v = tmp[i];
        int pos = atomicAdd(&cur[v >> 17], 1);
        col[pos] = v & 0x1FFFF;
    }
}

// ---------------- W1 transpose/convert: Wt[c][k] = bf16(W1[k][c]), k padded to 320 ----------------

__global__ __launch_bounds__(256) void wt1_kernel(const float* __restrict__ W,
                                                  unsigned short* __restrict__ Wt) {
    int idx = blockIdx.x * 256 + threadIdx.x;   // 64*320 = 20480
    if (idx >= 64 * 320) return;
    int c = idx / 320, k = idx - c * 320;
    float v = (k < 300) ? W[(size_t)k * 64 + c] : 0.f;
    Wt[idx] = f2bf(v);
}

// ---------------- GEMM 1 (MFMA bf16): h1(bf16) = x @ W1, fused e_src/e_dst ----------------
// Copy-pattern staging: block owns 48 CONSECUTIVE rows = 57.6 KB contiguous of x.
// Each global_load_lds covers 1024 contiguous bytes (lane i -> base + i*16) -- the
// exact pattern that hits 6.3 TB/s in the copy ubench. LDS is a verbatim image of
// the region (row stride 1200 B = 12 banks mod 32 -> fragment ds_read_b128 is
// naturally bank-uniform, no swizzle). One barrier total; K-loop is LDS+MFMA only.
// B fragments come from pre-transposed bf16 Wt (40 KB, L2/L3-hot), prefetched one
// tile ahead. 192 thr = 3 waves, wave w owns rows w*16..w*16+15 (one 16x64 strip).

#define G1_ROWS 48
#define G1_BYTES (G1_ROWS * 1200)            // 57600
#define G1_INSTR ((G1_BYTES + 1023) / 1024)  // 57 (3 waves x 19)

__global__ __launch_bounds__(192) void gemm1_mfma_kernel(
    const float* __restrict__ x, const unsigned short* __restrict__ Wt,
    const float* __restrict__ asrc, const float* __restrict__ adst,
    unsigned short* __restrict__ hbf, float* __restrict__ es, float* __restrict__ ed, int N) {
    __shared__ __align__(16) float A_lds[G1_INSTR * 256];   // 58368 B, verbatim x image
    const int tx = threadIdx.x;
    const int wv = tx >> 6;          // 0..2
    const int lane = tx & 63;
    const int l15 = lane & 15;
    const int quad = lane >> 4;
    const int rowBase = blockIdx.x * G1_ROWS;

    // ---- stage: contiguous 1 KB per instruction, clamped at buffer end ----
    {
        const size_t regionByte = (size_t)rowBase * 1200;
        const size_t lastOK = (size_t)N * 1200 - 16;
        const char* xb = (const char*)x;
#pragma unroll
        for (int j = 0; j < 19; j++) {
            int i = wv + 3 * j;                       // 0..56, disjoint across waves
            size_t g = regionByte + (size_t)i * 1024 + (size_t)lane * 16;
            if (g > lastOK) g = lastOK;
            glds16(xb + g, (char*)A_lds + i * 1024);
        }
    }

    // ---- B fragments for tile 0 while staging is in flight ----
    const unsigned short* wtl = Wt + (size_t)l15 * 320 + quad * 8;  // + ct*16*320 + t*32
    ushort8 bcur[4];
#pragma unroll
    for (int ct = 0; ct < 4; ct++) bcur[ct] = *(const ushort8*)(wtl + ct * 16 * 320);

    f32x4 acc[4];
#pragma unroll
    for (int ct = 0; ct < 4; ct++) acc[ct] = (f32x4){0.f, 0.f, 0.f, 0.f};

    __syncthreads();   // staging + all waves' glds complete

    const float* arow = &A_lds[(wv * 16 + l15) * 300 + quad * 8];
#pragma unroll
    for (int t = 0; t < 10; t++) {
        ushort8 bnext[4];
        if (t < 9) {
#pragma unroll
            for (int ct = 0; ct < 4; ct++)
                bnext[ct] = *(const ushort8*)(wtl + ct * 16 * 320 + (t + 1) * 32);
        }
        // A fragment: 8 floats (two b128) -> bf16x8. Tail tile (k>=288): rows have
        // only k<300 valid; k=296..299 real, the ds_read past 300 reads the next
        // row's data -> junk, but Wt rows are zero for k>=300, annihilating it.
        f32x4 fa = *(const f32x4*)(arow + t * 32);
        f32x4 fb = *(const f32x4*)(arow + t * 32 + 4);
        union { unsigned u[4]; short8 s; } cv;
        cv.u[0] = cvt2(fa[0], fa[1]);
        cv.u[1] = cvt2(fa[2], fa[3]);
        cv.u[2] = cvt2(fb[0], fb[1]);
        cv.u[3] = cvt2(fb[2], fb[3]);
#pragma unroll
        for (int ct = 0; ct < 4; ct++) {
            short8 bfr;
            __builtin_memcpy(&bfr, &bcur[ct], 16);
            acc[ct] = __builtin_amdgcn_mfma_f32_16x16x32_bf16(cv.s, bfr, acc[ct], 0, 0, 0);
        }
#pragma unroll
        for (int ct = 0; ct < 4; ct++) bcur[ct] = bnext[ct];
    }

    float as_v[4], ad_v[4];
#pragma unroll
    for (int ct = 0; ct < 4; ct++) {
        as_v[ct] = asrc[ct * 16 + l15];
        ad_v[ct] = adst[ct * 16 + l15];
    }
#pragma unroll
    for (int reg = 0; reg < 4; reg++) {
        int row = rowBase + wv * 16 + quad * 4 + reg;
        bool ok = (row < N);
#pragma unroll
        for (int ct = 0; ct < 4; ct++) {
            float v = acc[ct][reg];
            if (ok) hbf[(size_t)row * 64 + ct * 16 + l15] = f2bf(v);
            float ps = v * as_v[ct];
            float pd = v * ad_v[ct];
            ps += __shfl_xor(ps, 1); ps += __shfl_xor(ps, 2); ps += __shfl_xor(ps, 4);
            pd += __shfl_xor(pd, 1); pd += __shfl_xor(pd, 2); pd += __shfl_xor(pd, 4);
            if ((lane & 7) == 0 && ok) {
                int head = 2 * ct + ((lane >> 3) & 1);
                es[row * 8 + head] = ps;
                ed[row * 8 + head] = pd;
            }
        }
    }
}

// ---------------- GEMM 2 (MFMA bf16): h2(bf16) = h1p(bf16) @ W2, fused scalar e_src/e_dst ----------------

__global__ __launch_bounds__(256) void gemm2_mfma_kernel(
    const unsigned short* __restrict__ xin, const float* __restrict__ W,
    const float* __restrict__ asrc, const float* __restrict__ adst,
    unsigned short* __restrict__ hbf, float* __restrict__ es, float* __restrict__ ed, int N) {
    __shared__ __align__(16) unsigned short A_lds[128 * 72];
    __shared__ __align__(16) unsigned short B_lds[64 * 72];
    const int tx = threadIdx.x;
    const int wv = tx >> 6;
    const int lane = tx & 63;
    const int l15 = lane & 15;
    const int quad = lane >> 4;
    const int rowBase = blockIdx.x * 128;

    f32x4 acc[2][4];
#pragma unroll
    for (int rt = 0; rt < 2; rt++)
#pragma unroll
        for (int ct = 0; ct < 4; ct++) acc[rt][ct] = (f32x4){0.f, 0.f, 0.f, 0.f};

    // stage B: full 64x64 (transposed into [col][k], stride 72)
    {
        int colB = tx & 63;
        int kk = (tx >> 6) * 16;
#pragma unroll
        for (int j = 0; j < 16; j++)
            B_lds[colB * 72 + kk + j] = f2bf(W[(size_t)(kk + j) * 64 + colB]);
    }
    // stage A: 128 rows x 64 k, bf16 input -> straight copy (ushort8 = 16B loads)
    {
        int kq = tx & 7, r0 = tx >> 3;
        const ushort8 z = (ushort8){0, 0, 0, 0, 0, 0, 0, 0};
#pragma unroll
        for (int p = 0; p < 4; p++) {
            int row = p * 32 + r0;
            int grow = rowBase + row;
            ushort8 v = z;
            if (grow < N) v = *(const ushort8*)&xin[(size_t)grow * 64 + kq * 8];
            *(ushort8*)&A_lds[row * 72 + kq * 8] = v;
        }
    }
    __syncthreads();
#pragma unroll
    for (int c = 0; c < 2; c++) {
        short8 af[2], bfr[4];
#pragma unroll
        for (int rt = 0; rt < 2; rt++)
            af[rt] = *(const short8*)&A_lds[(wv * 32 + rt * 16 + l15) * 72 + quad * 8 + c * 32];
#pragma unroll
        for (int ct = 0; ct < 4; ct++)
            bfr[ct] = *(const short8*)&B_lds[(ct * 16 + l15) * 72 + quad * 8 + c * 32];
#pragma unroll
        for (int rt = 0; rt < 2; rt++)
#pragma unroll
            for (int ct = 0; ct < 4; ct++)
                acc[rt][ct] = __builtin_amdgcn_mfma_f32_16x16x32_bf16(af[rt], bfr[ct], acc[rt][ct], 0, 0, 0);
    }

    float as_v[4], ad_v[4];
#pragma unroll
    for (int ct = 0; ct < 4; ct++) {
        as_v[ct] = asrc[ct * 16 + l15];
        ad_v[ct] = adst[ct * 16 + l15];
    }
#pragma unroll
    for (int rt = 0; rt < 2; rt++) {
#pragma unroll
        for (int reg = 0; reg < 4; reg++) {
            int row = rowBase + wv * 32 + rt * 16 + quad * 4 + reg;
            bool ok = (row < N);
            float ps = 0.f, pd = 0.f;
#pragma unroll
            for (int ct = 0; ct < 4; ct++) {
                float v = acc[rt][ct][reg];
                if (ok) hbf[(size_t)row * 64 + ct * 16 + l15] = f2bf(v);
                ps = fmaf(v, as_v[ct], ps);
                pd = fmaf(v, ad_v[ct], pd);
            }
            ps += __shfl_xor(ps, 1); ps += __shfl_xor(ps, 2);
            ps += __shfl_xor(ps, 4); ps += __shfl_xor(ps, 8);
            pd += __shfl_xor(pd, 1); pd += __shfl_xor(pd, 2);
            pd += __shfl_xor(pd, 4); pd += __shfl_xor(pd, 8);
            if (l15 == 0 && ok) { es[row] = ps; ed[row] = pd; }
        }
    }
}

// ---------------- fused aggregations: softmax weights computed inline ----------------
// lane = 32*half + fl; lane handles features {2fl, 2fl+1} of edge (i + 2j + half).
// Softmax shift dropped (logits bounded, clamp at 30); denominator accumulated inline.
// Out-of-range edge slots clamp their index to `beg` (every node has a self-loop so
// end > beg): the wasted gathers hit already-fetched lines instead of scattering.

__global__ __launch_bounds__(256) void agg1f_kernel(
    const int* __restrict__ rowptr, const int* __restrict__ col,
    const unsigned short* __restrict__ hbf, const float* __restrict__ es,
    const float* __restrict__ ed, const float* __restrict__ b,
    unsigned int* __restrict__ outbf, int N) {
    int node = blockIdx.x * 4 + (threadIdx.x >> 6);
    int lane = threadIdx.x & 63;
    if (node >= N) return;
    int half = lane >> 5, fl = lane & 31;
    int f0 = fl * 2, hh = fl >> 2;
    int beg = rowptr[node], end = rowptr[node + 1];
    float edv = ed[node * 8 + hh];
    float acc0 = 0.f, acc1 = 0.f, lsum = 0.f;
    for (int i = beg; i < end; i += 16) {
        int ei_[EB], ss[EB];
        float ev[EB];
        unsigned hp[EB];
#pragma unroll
        for (int j = 0; j < EB; j++) ei_[j] = i + 2 * j + half;
#pragma unroll
        for (int j = 0; j < EB; j++) ss[j] = col[(ei_[j] < end) ? ei_[j] : beg];
#pragma unroll
        for (int j = 0; j < EB; j++) ev[j] = es[ss[j] * 8 + hh];
#pragma unroll
        for (int j = 0; j < EB; j++) hp[j] = *(const unsigned*)&hbf[(size_t)ss[j] * 64 + f0];
#pragma unroll
        for (int j = 0; j < EB; j++) {
            float e = ev[j] + edv;
            e = (e > 0.f) ? e : 0.2f * e;
            float wj = __expf(fminf(e, 30.f));
            wj = (ei_[j] < end) ? wj : 0.f;
            lsum += wj;
            float lo = __uint_as_float(hp[j] << 16);
            float hi = __uint_as_float(hp[j] & 0xFFFF0000u);
            acc0 = fmaf(wj, lo, acc0);
            acc1 = fmaf(wj, hi, acc1);
        }
    }
    acc0 += __shfl_xor(acc0, 32);
    acc1 += __shfl_xor(acc1, 32);
    lsum += __shfl_xor(lsum, 32);
    float rinv = 1.f / lsum;
    float o0 = acc0 * rinv + b[f0];
    float o1 = acc1 * rinv + b[f0 + 1];
    o0 = (o0 > 0.f) ? o0 : expm1f(o0);
    o1 = (o1 > 0.f) ? o1 : expm1f(o1);
    if (half == 0) {
        unsigned pk = (unsigned)f2bf(o0) | ((unsigned)f2bf(o1) << 16);
        outbf[((size_t)node * 64 + f0) >> 1] = pk;
    }
}

__global__ __launch_bounds__(256) void agg2f_kernel(
    const int* __restrict__ rowptr, const int* __restrict__ col,
    const unsigned short* __restrict__ hbf, const float* __restrict__ es,
    const float* __restrict__ ed, const float* __restrict__ b,
    float* __restrict__ out, int N) {
    int node = blockIdx.x * 4 + (threadIdx.x >> 6);
    int lane = threadIdx.x & 63;
    if (node >= N) return;
    int half = lane >> 5, fl = lane & 31;
    int f0 = fl * 2;
    int beg = rowptr[node], end = rowptr[node + 1];
    float edv = ed[node];
    float acc0 = 0.f, acc1 = 0.f, lsum = 0.f;
    for (int i = beg; i < end; i += 16) {
        int ei_[EB], ss[EB];
        float ev[EB];
        unsigned hp[EB];
#pragma unroll
        for (int j = 0; j < EB; j++) ei_[j] = i + 2 * j + half;
#pragma unroll
        for (int j = 0; j < EB; j++) ss[j] = col[(ei_[j] < end) ? ei_[j] : beg];
#pragma unroll
        for (int j = 0; j < EB; j++) ev[j] = es[ss[j]];
#pragma unroll
        for (int j = 0; j < EB; j++) hp[j] = *(const unsigned*)&hbf[(size_t)ss[j] * 64 + f0];
#pragma unroll
        for (int j = 0; j < EB; j++) {
            float e = ev[j] + edv;
            e = (e > 0.f) ? e : 0.2f * e;
            float wj = __expf(fminf(e, 30.f));
            wj = (ei_[j] < end) ? wj : 0.f;
            lsum += wj;
            float lo = __uint_as_float(hp[j] << 16);
            float hi = __uint_as_float(hp[j] & 0xFFFF0000u);
            acc0 = fmaf(wj, lo, acc0);
            acc1 = fmaf(wj, hi, acc1);
        }
    }
    acc0 += __shfl_xor(acc0, 32);
    acc1 += __shfl_xor(acc1, 32);
    lsum += __shfl_xor(lsum, 32);
    float rinv = 1.f / lsum;
    float o0 = acc0 * rinv + b[f0];
    float o1 = acc1 * rinv + b[f0 + 1];
    // log_softmax over 64 features (each half holds all 32 feature-pairs after combine)
    float M = fmaxf(o0, o1);
    M = fmaxf(M, __shfl_xor(M, 1));  M = fmaxf(M, __shfl_xor(M, 2));
    M = fmaxf(M, __shfl_xor(M, 4));  M = fmaxf(M, __shfl_xor(M, 8));
    M = fmaxf(M, __shfl_xor(M, 16));
    float se = __expf(o0 - M) + __expf(o1 - M);
    se += __shfl_xor(se, 1);  se += __shfl_xor(se, 2);
    se += __shfl_xor(se, 4);  se += __shfl_xor(se, 8);
    se += __shfl_xor(se, 16);
    float ls = logf(se);
    if (half == 0) {
        float2 r = make_float2(o0 - M - ls, o1 - M - ls);
        *(float2*)&out[(size_t)node * 64 + f0] = r;
    }
}

// ---------------- launch ----------------

extern "C" void kernel_launch(void* const* d_in, const int* in_sizes, int n_in,
                              void* d_out, int out_size, void* d_ws, size_t ws_size,
                              hipStream_t stream) {
    const float* x   = (const float*)d_in[0];
    const int*   ei  = (const int*)d_in[1];
    const float* W1  = (const float*)d_in[2];
    const float* as1 = (const float*)d_in[3];
    const float* ad1 = (const float*)d_in[4];
    const float* b1  = (const float*)d_in[5];
    const float* W2  = (const float*)d_in[6];
    const float* as2 = (const float*)d_in[7];
    const float* ad2 = (const float*)d_in[8];
    const float* b2  = (const float*)d_in[9];
    const int N = in_sizes[0] / 300;
    const int E = in_sizes[1] / 2;
    const int Etot = E + N;
    const int nbuck = (N + 127) >> 7;   // <= 800
    (void)n_in; (void)out_size; (void)ws_size;

    char* w = (char*)d_ws;
    auto alloc = [&](size_t bytes) -> char* {
        char* p = w;
        w += (bytes + 255) & ~(size_t)255;
        return p;
    };
    int*   flag        = (int*)alloc(256);
    int*   hist        = (int*)alloc((size_t)NBLKS * BPAD * 4);
    int*   bucketTotal = (int*)alloc((size_t)(BPAD + 1) * 4);
    int*   bucketBase  = (int*)alloc((size_t)(BPAD + 1) * 4);
    int*   tmp         = (int*)alloc((size_t)(Etot + 16) * 4);
    int*   rowptr      = (int*)alloc((size_t)(N + 1) * 4);
    int*   col         = (int*)alloc((size_t)(Etot + 16) * 4);
    unsigned short* h1  = (unsigned short*)alloc((size_t)N * 64 * 2);
    unsigned short* h1p = (unsigned short*)alloc((size_t)N * 64 * 2);
    float* es1         = (float*)alloc((size_t)N * 8 * 4);
    float* ed1         = (float*)alloc((size_t)N * 8 * 4);
    float* es2         = (float*)alloc((size_t)N * 4);
    float* ed2         = (float*)alloc((size_t)N * 4);
    unsigned short* Wt1 = (unsigned short*)alloc((size_t)64 * 320 * 2);
    unsigned short* h2 = h1;        // h1 dead after agg1

    detect64_kernel<<<1, 256, 0, stream>>>(ei, E, flag);

    int chunk = (Etot + NBLKS - 1) / NBLKS;
    binA_kernel<<<NBLKS, 256, 0, stream>>>(ei, E, N, flag, nbuck, hist, chunk);
    scanBlocks_kernel<<<(nbuck + 255) / 256, 256, 0, stream>>>(hist, nbuck, bucketTotal);
    scanBucket_kernel<<<1, 1024, 0, stream>>>(bucketTotal, nbuck, bucketBase);
    binB_kernel<<<NBLKS, 256, 0, stream>>>(ei, E, N, flag, nbuck, hist, bucketBase, tmp, chunk);
    binC_kernel<<<nbuck, 256, 0, stream>>>(tmp, bucketBase, nbuck, N, Etot, rowptr, col);

    wt1_kernel<<<(64 * 320 + 255) / 256, 256, 0, stream>>>(W1, Wt1);
    gemm1_mfma_kernel<<<(N + G1_ROWS - 1) / G1_ROWS, 192, 0, stream>>>(
        x, Wt1, as1, ad1, h1, es1, ed1, N);
    agg1f_kernel<<<(N + 3) / 4, 256, 0, stream>>>(rowptr, col, h1, es1, ed1, b1,
                                                  (unsigned int*)h1p, N);
    gemm2_mfma_kernel<<<(N + 127) / 128, 256, 0, stream>>>(h1p, W2, as2, ad2, h2, es2, ed2, N);
    agg2f_kernel<<<(N + 3) / 4, 256, 0, stream>>>(rowptr, col, h2, es2, ed2, b2, (float*)d_out, N);
}